// Round 9
// baseline (69.929 us; speedup 1.0000x reference)
//
#include <hip/hip_runtime.h>
#include <math.h>

namespace {
constexpr int NB = 2048;      // batch
constexpr int NNODE = 6;      // nodes
constexpr int DD = 2048;      // feature dim
constexpr int HH = 1024;      // hidden
constexpr int CC = 200;       // classes
constexpr int K2 = 2 * DD;    // 4096 (concat dim)
constexpr int NPAD = 256;     // padded class dim
constexpr int ZS1 = 4;        // split-K for g1 (K per z = 256)
constexpr int ZS2 = 16;       // split-K for gemm2 (K per z = 256)
constexpr float ALPHA_C = 0.015f;
constexpr float SCALE_C = 24.0f;

constexpr int G1_BLOCKS = (K2 / 32) * ZS1;   // 512
}

typedef __attribute__((ext_vector_type(8))) short bf16x8;
typedef __attribute__((ext_vector_type(4))) float f32x4;

static __device__ __forceinline__ unsigned short f2bf(float x) {
    union { float f; unsigned int u; } v; v.f = x;
    unsigned int r = v.u + 0x7FFFu + ((v.u >> 16) & 1u);  // RNE
    return (unsigned short)(r >> 16);
}

static __device__ __forceinline__ float bf2f(unsigned short u) {
    union { unsigned int i; float f; } v; v.i = ((unsigned int)u) << 16;
    return v.f;
}

// ---------------------------------------------------------------------------
// Wave-parallel node weights (lane u*8+v computes one exp+sqrt).
// ---------------------------------------------------------------------------
static __device__ __forceinline__ void compute_s_wave(const float* __restrict__ cdds,
                                                      int b, float sv[NNODE]) {
    const int lane = threadIdx.x & 63;
    const int u = lane >> 3;      // 0..7
    const int v = lane & 7;       // 0..7
    const float* cd = cdds + (size_t)b * 36;
    float w = 0.f;
    const bool valid = (u < 6) & (v < 6) & (u != v);
    if (u < 6 && v < 6 && u != v) {
        float cyu = (cd[u * 6 + 1] + cd[u * 6 + 3]) * 0.5f;
        float cxu = (cd[u * 6 + 2] + cd[u * 6 + 4]) * 0.5f;
        float cyv = (cd[v * 6 + 1] + cd[v * 6 + 3]) * 0.5f;
        float cxv = (cd[v * 6 + 2] + cd[v * 6 + 4]) * 0.5f;
        float dx = cxu - cxv, dy = cyu - cyv;
        w = expf(-ALPHA_C * sqrtf(dx * dx + dy * dy));
    }
    float s = w;
#pragma unroll
    for (int m = 32; m >= 1; m >>= 1) s += __shfl_xor(s, m);
    float mean = s * (1.f / 30.f);
    float tt = valid ? fmaxf(w - mean, 0.f) : 0.f;
    tt += __shfl_xor(tt, 1);
    tt += __shfl_xor(tt, 2);
    tt += __shfl_xor(tt, 4);
    float su = SCALE_C * tt * 0.2f;   // s[u] for this lane's row u
#pragma unroll
    for (int uu = 0; uu < NNODE; ++uu) sv[uu] = __shfl(su, uu * 8);
}

// ---------------------------------------------------------------------------
// k_small: blocks [0,64): cls_w -> cls_wT bf16 [256][1024] (transposed, pad)
//          blocks [64,89): bvec[c] = fc_b @ cls_w + cls_b
// ---------------------------------------------------------------------------
__global__ __launch_bounds__(256) void k_small(const float* __restrict__ cls_w,
                                               const float* __restrict__ fc_b,
                                               const float* __restrict__ cls_b,
                                               unsigned short* __restrict__ cls_wT,
                                               float* __restrict__ bvec)
{
    __shared__ float sm[64 * 65];
    const int bx = blockIdx.x;
    const int t = threadIdx.x;
    if (bx >= 64) {
        const int bb = bx - 64;           // 0..24
        float* red = sm;
        int c8 = t & 7;
        int hs = t >> 3;
        int c = bb * 8 + c8;              // < 200
        float acc = 0.f;
        for (int h = hs; h < HH; h += 32)
            acc += fc_b[h] * cls_w[(size_t)h * CC + c];
        red[t] = acc;
        __syncthreads();
        for (int s = 128; s >= 8; s >>= 1) {
            if (t < s) red[t] += red[t + s];
            __syncthreads();
        }
        if (t < 8) bvec[c] = red[t] + cls_b[c];
        return;
    }
    const int kt = bx & 15;
    const int nt = bx >> 4;
#pragma unroll
    for (int c = 0; c < 4; ++c) {
        int i = t + c * 256;
        int kr = i >> 4;
        int n4 = (i & 15) << 2;
        int gn = nt * 64 + n4;
        const float* sp = cls_w + (size_t)(kt * 64 + kr) * CC + gn;
        float4 v = {0.f, 0.f, 0.f, 0.f};
        if (gn + 3 < CC) {
            v = *(const float4*)sp;
        } else {
            if (gn + 0 < CC) v.x = sp[0];
            if (gn + 1 < CC) v.y = sp[1];
            if (gn + 2 < CC) v.z = sp[2];
            if (gn + 3 < CC) v.w = sp[3];
        }
        sm[kr * 65 + n4 + 0] = v.x; sm[kr * 65 + n4 + 1] = v.y;
        sm[kr * 65 + n4 + 2] = v.z; sm[kr * 65 + n4 + 3] = v.w;
    }
    __syncthreads();
#pragma unroll
    for (int c = 0; c < 4; ++c) {
        int i = t + c * 256;
        int nr = i >> 4;
        int k4 = (i & 15) << 2;
        ushort4 o;
        o.x = f2bf(sm[(k4 + 0) * 65 + nr]);
        o.y = f2bf(sm[(k4 + 1) * 65 + nr]);
        o.z = f2bf(sm[(k4 + 2) * 65 + nr]);
        o.w = f2bf(sm[(k4 + 3) * 65 + nr]);
        *(ushort4*)(cls_wT + (size_t)(nt * 64 + nr) * HH + kt * 64 + k4) = o;
    }
}

// ---------------------------------------------------------------------------
// k_mid: blocks [0,512):    g1: partM[z][4096][256] = fc_w @ cls_w (f32,
//                           split-K=4, tile 32x256) — MFMA/L2-bound.
//        blocks [512,4608): pq streaming — HBM-bound. Co-scheduled: g1 hides
//                           under the pq stream.
// ---------------------------------------------------------------------------
__global__ __launch_bounds__(256) void k_mid(const float* __restrict__ pf,
                                             const float* __restrict__ cdds,
                                             const float* __restrict__ fc_w,
                                             const unsigned short* __restrict__ Bt,
                                             unsigned short* __restrict__ pq,
                                             float* __restrict__ partM)
{
    __shared__ short As[32][72];
    __shared__ short Bs[256][72];
    const int bx = blockIdx.x;
    const int t = threadIdx.x;

    if (bx >= G1_BLOCKS) {
        // ---------------- pq streaming ----------------
        const int bid = bx - G1_BLOCKS;
        const int b = bid >> 1;
        const int d = ((bid & 1) << 10) + (t << 2);
        const float* base = pf + (size_t)b * NNODE * DD + d;
        float4 v0 = *(const float4*)(base + 0 * DD);
        float4 v1 = *(const float4*)(base + 1 * DD);
        float4 v2 = *(const float4*)(base + 2 * DD);
        float4 v3 = *(const float4*)(base + 3 * DD);
        float4 v4 = *(const float4*)(base + 4 * DD);
        float4 v5 = *(const float4*)(base + 5 * DD);

        float sv[NNODE];
        compute_s_wave(cdds, b, sv);

        float4 q;
        q.x = v0.x + v1.x + v2.x + v3.x + v4.x + v5.x;
        q.y = v0.y + v1.y + v2.y + v3.y + v4.y + v5.y;
        q.z = v0.z + v1.z + v2.z + v3.z + v4.z + v5.z;
        q.w = v0.w + v1.w + v2.w + v3.w + v4.w + v5.w;

        float4 p = {0.f, 0.f, 0.f, 0.f};
        p.x = fmaf(sv[0], v0.x, p.x); p.y = fmaf(sv[0], v0.y, p.y);
        p.z = fmaf(sv[0], v0.z, p.z); p.w = fmaf(sv[0], v0.w, p.w);
        p.x = fmaf(sv[1], v1.x, p.x); p.y = fmaf(sv[1], v1.y, p.y);
        p.z = fmaf(sv[1], v1.z, p.z); p.w = fmaf(sv[1], v1.w, p.w);
        p.x = fmaf(sv[2], v2.x, p.x); p.y = fmaf(sv[2], v2.y, p.y);
        p.z = fmaf(sv[2], v2.z, p.z); p.w = fmaf(sv[2], v2.w, p.w);
        p.x = fmaf(sv[3], v3.x, p.x); p.y = fmaf(sv[3], v3.y, p.y);
        p.z = fmaf(sv[3], v3.z, p.z); p.w = fmaf(sv[3], v3.w, p.w);
        p.x = fmaf(sv[4], v4.x, p.x); p.y = fmaf(sv[4], v4.y, p.y);
        p.z = fmaf(sv[4], v4.z, p.z); p.w = fmaf(sv[4], v4.w, p.w);
        p.x = fmaf(sv[5], v5.x, p.x); p.y = fmaf(sv[5], v5.y, p.y);
        p.z = fmaf(sv[5], v5.z, p.z); p.w = fmaf(sv[5], v5.w, p.w);

        unsigned short* o = pq + (size_t)b * K2;
        ushort4 pb, qb;
        pb.x = f2bf(p.x); pb.y = f2bf(p.y); pb.z = f2bf(p.z); pb.w = f2bf(p.w);
        qb.x = f2bf(q.x); qb.y = f2bf(q.y); qb.z = f2bf(q.z); qb.w = f2bf(q.w);
        *(ushort4*)(o + d) = pb;
        *(ushort4*)(o + DD + d) = qb;
        return;
    }

    // ---------------- g1 ----------------
    const int lane = t & 63;
    const int wid = t >> 6;
    const int bm = (bx >> 2) * 32;
    const int z = bx & 3;
    const int kbase = z * (HH / ZS1);   // 256

    f32x4 acc[2][4] = {};

    for (int k0 = kbase; k0 < kbase + HH / ZS1; k0 += 64) {
#pragma unroll
        for (int c = 0; c < 2; ++c) {
            int i = t + c * 256;
            int row = i >> 4;              // 0..31
            int k4 = (i & 15) << 2;
            float4 v = *(const float4*)(fc_w + (size_t)(bm + row) * HH + k0 + k4);
            ushort4 o;
            o.x = f2bf(v.x); o.y = f2bf(v.y); o.z = f2bf(v.z); o.w = f2bf(v.w);
            *(ushort4*)&As[row][k4] = o;
        }
#pragma unroll
        for (int c = 0; c < 8; ++c) {
            int i = t + c * 256;
            int n = i >> 3;                // 0..255
            int k8 = (i & 7) << 3;
            *(uint4*)&Bs[n][k8] =
                *(const uint4*)(Bt + (size_t)n * HH + k0 + k8);
        }
        __syncthreads();
#pragma unroll
        for (int ks = 0; ks < 2; ++ks) {
            int kk = ks * 32 + ((lane >> 4) << 3);
            int ar = lane & 15;
            bf16x8 a0 = *(const bf16x8*)&As[ar][kk];
            bf16x8 a1 = *(const bf16x8*)&As[16 + ar][kk];
#pragma unroll
            for (int fn = 0; fn < 4; ++fn) {
                bf16x8 b = *(const bf16x8*)&Bs[wid * 64 + fn * 16 + ar][kk];
                acc[0][fn] = __builtin_amdgcn_mfma_f32_16x16x32_bf16(a0, b, acc[0][fn], 0, 0, 0);
                acc[1][fn] = __builtin_amdgcn_mfma_f32_16x16x32_bf16(a1, b, acc[1][fn], 0, 0, 0);
            }
        }
        __syncthreads();
    }
#pragma unroll
    for (int fm = 0; fm < 2; ++fm)
#pragma unroll
        for (int fn = 0; fn < 4; ++fn) {
            int gm0 = bm + fm * 16 + ((lane >> 4) << 2);
            int gn = wid * 64 + fn * 16 + (lane & 15);
#pragma unroll
            for (int r = 0; r < 4; ++r)
                partM[((size_t)z * K2 + gm0 + r) * NPAD + gn] = acc[fm][fn][r];
        }
}

// ---------------------------------------------------------------------------
// k_red: Mt[n][m] bf16 = sum_z partM[z][m][n] (64x64 LDS transpose tiles)
// ---------------------------------------------------------------------------
__global__ __launch_bounds__(256) void k_red(const float* __restrict__ partM,
                                             unsigned short* __restrict__ Mt)
{
    __shared__ float sm[64][69];
    const int bx = blockIdx.x;
    const int t = threadIdx.x;
    const int bm = (bx >> 2) * 64;        // m-tile (4096)
    const int bn = (bx & 3) * 64;         // n-tile (256)
#pragma unroll
    for (int c = 0; c < 4; ++c) {
        int i = t + c * 256;
        int mr = i >> 4;                  // 0..63
        int n4 = (i & 15) << 2;
        float4 s = {0.f, 0.f, 0.f, 0.f};
#pragma unroll
        for (int z = 0; z < ZS1; ++z) {
            float4 v = *(const float4*)(partM +
                ((size_t)z * K2 + bm + mr) * NPAD + bn + n4);
            s.x += v.x; s.y += v.y; s.z += v.z; s.w += v.w;
        }
        sm[mr][n4 + 0] = s.x; sm[mr][n4 + 1] = s.y;
        sm[mr][n4 + 2] = s.z; sm[mr][n4 + 3] = s.w;
    }
    __syncthreads();
#pragma unroll
    for (int c = 0; c < 4; ++c) {
        int i = t + c * 256;
        int nr = i >> 4;                  // 0..63
        int m4 = (i & 15) << 2;
        ushort4 o;
        o.x = f2bf(sm[m4 + 0][nr]);
        o.y = f2bf(sm[m4 + 1][nr]);
        o.z = f2bf(sm[m4 + 2][nr]);
        o.w = f2bf(sm[m4 + 3][nr]);
        *(ushort4*)(Mt + (size_t)(bn + nr) * K2 + bm + m4) = o;
    }
}

// ---------------------------------------------------------------------------
// GEMM2: part[z][2048][256] bf16 = pq @ Mt^T partial (split-K=16)
// grid (32, 16) = 512 blocks. Block 64m x 256n; wave tile 64m x 64n,
// acc[4][4]: 8 ds_reads per 16 MFMA.
// ---------------------------------------------------------------------------
__global__ __launch_bounds__(256) void k_gemm2(const unsigned short* __restrict__ A,
                                               const unsigned short* __restrict__ Bt,
                                               unsigned short* __restrict__ part)
{
    __shared__ short As[64][72];    // 9.2 KB
    __shared__ short Bs[256][72];   // 36.9 KB
    const int t = threadIdx.x;
    const int lane = t & 63;
    const int wid = t >> 6;         // n-strip
    const int bm = blockIdx.x * 64;
    const int z = blockIdx.y;
    const int kbase = z * (K2 / ZS2);   // 256 per z

    f32x4 acc[4][4] = {};

    for (int k0 = kbase; k0 < kbase + K2 / ZS2; k0 += 64) {
#pragma unroll
        for (int c = 0; c < 2; ++c) {
            int i = t + c * 256;
            int row = i >> 3;
            int k8 = (i & 7) << 3;
            *(uint4*)&As[row][k8] =
                *(const uint4*)(A + (size_t)(bm + row) * K2 + k0 + k8);
        }
#pragma unroll
        for (int c = 0; c < 8; ++c) {
            int i = t + c * 256;
            int n = i >> 3;
            int k8 = (i & 7) << 3;
            *(uint4*)&Bs[n][k8] =
                *(const uint4*)(Bt + (size_t)n * K2 + k0 + k8);
        }
        __syncthreads();
#pragma unroll
        for (int ks = 0; ks < 2; ++ks) {
            int kk = ks * 32 + ((lane >> 4) << 3);
            int ar = lane & 15;
            bf16x8 a0 = *(const bf16x8*)&As[0 * 16 + ar][kk];
            bf16x8 a1 = *(const bf16x8*)&As[1 * 16 + ar][kk];
            bf16x8 a2 = *(const bf16x8*)&As[2 * 16 + ar][kk];
            bf16x8 a3 = *(const bf16x8*)&As[3 * 16 + ar][kk];
#pragma unroll
            for (int fn = 0; fn < 4; ++fn) {
                bf16x8 b = *(const bf16x8*)&Bs[wid * 64 + fn * 16 + ar][kk];
                acc[0][fn] = __builtin_amdgcn_mfma_f32_16x16x32_bf16(a0, b, acc[0][fn], 0, 0, 0);
                acc[1][fn] = __builtin_amdgcn_mfma_f32_16x16x32_bf16(a1, b, acc[1][fn], 0, 0, 0);
                acc[2][fn] = __builtin_amdgcn_mfma_f32_16x16x32_bf16(a2, b, acc[2][fn], 0, 0, 0);
                acc[3][fn] = __builtin_amdgcn_mfma_f32_16x16x32_bf16(a3, b, acc[3][fn], 0, 0, 0);
            }
        }
        __syncthreads();
    }
#pragma unroll
    for (int fm = 0; fm < 4; ++fm)
#pragma unroll
        for (int fn = 0; fn < 4; ++fn) {
            int gm0 = bm + fm * 16 + ((lane >> 4) << 2);
            int gn = wid * 64 + fn * 16 + (lane & 15);
#pragma unroll
            for (int r = 0; r < 4; ++r)
                part[((size_t)z * NB + gm0 + r) * NPAD + gn] = f2bf(acc[fm][fn][r]);
        }
}

// ---------------------------------------------------------------------------
// out[b,c0..c0+3] = (sum_z part[z][b][c]) / 6 + bvec[c]
// ---------------------------------------------------------------------------
__global__ __launch_bounds__(256) void k_combine(const unsigned short* __restrict__ part,
                                                 const float* __restrict__ bvec,
                                                 float* __restrict__ out)
{
    int idx = blockIdx.x * blockDim.x + threadIdx.x;   // NB * 50
    if (idx >= NB * (CC / 4)) return;
    int b = idx / (CC / 4);
    int c0 = (idx - b * (CC / 4)) << 2;
    float s0 = 0.f, s1 = 0.f, s2 = 0.f, s3 = 0.f;
#pragma unroll
    for (int z = 0; z < ZS2; ++z) {
        ushort4 v = *(const ushort4*)(part + ((size_t)z * NB + b) * NPAD + c0);
        s0 += bf2f(v.x); s1 += bf2f(v.y); s2 += bf2f(v.z); s3 += bf2f(v.w);
    }
    float4 o;
    o.x = s0 * (1.f / 6.f) + bvec[c0 + 0];
    o.y = s1 * (1.f / 6.f) + bvec[c0 + 1];
    o.z = s2 * (1.f / 6.f) + bvec[c0 + 2];
    o.w = s3 * (1.f / 6.f) + bvec[c0 + 3];
    *(float4*)(out + (size_t)b * CC + c0) = o;
}

// ---------------------------------------------------------------------------
extern "C" void kernel_launch(void* const* d_in, const int* in_sizes, int n_in,
                              void* d_out, int out_size, void* d_ws, size_t ws_size,
                              hipStream_t stream)
{
    const float* part_feats = (const float*)d_in[0];
    const float* cdds = (const float*)d_in[1];
    const float* fc_w = (const float*)d_in[2];   // (4096, 1024)
    const float* fc_b = (const float*)d_in[3];   // (1024,)
    const float* cls_w = (const float*)d_in[4];  // (1024, 200)
    const float* cls_b = (const float*)d_in[5];  // (200,)
    float* out = (float*)d_out;                  // (2048, 200)

    char* ws = (char*)d_ws;
    size_t off = 0;
    unsigned short* pq = (unsigned short*)(ws + off);     off += (size_t)NB * K2 * 2;         // 16.8 MB
    unsigned short* Mt = (unsigned short*)(ws + off);     off += (size_t)NPAD * K2 * 2;       // 2.1 MB
    unsigned short* cls_wT = (unsigned short*)(ws + off); off += (size_t)NPAD * HH * 2;       // 0.5 MB
    float* partM = (float*)(ws + off);                    off += (size_t)ZS1 * K2 * NPAD * 4; // 16.8 MB
    unsigned short* part = (unsigned short*)(ws + off);   off += (size_t)ZS2 * NB * NPAD * 2; // 16.8 MB
    float* bvec = (float*)(ws + off);                     off += 256 * 4;

    // 1. cls_w -> cls_wT bf16 + bvec
    k_small<<<dim3(64 + 25), dim3(256), 0, stream>>>(cls_w, fc_b, cls_b, cls_wT, bvec);
    // 2. g1 (512 blocks, hides under) + pq stream (4096 blocks)
    k_mid<<<dim3(G1_BLOCKS + NB * 2), dim3(256), 0, stream>>>(
        part_feats, cdds, fc_w, cls_wT, pq, partM);
    // 3. reduce partM -> Mt bf16
    k_red<<<dim3(256), dim3(256), 0, stream>>>(partM, Mt);
    // 4. pq @ Mt^T partials (bf16), split-K=16
    k_gemm2<<<dim3(NB / 64, ZS2), dim3(256), 0, stream>>>(pq, Mt, part);
    // 5. combine + scale + bias
    k_combine<<<dim3((NB * (CC / 4) + 255) / 256), dim3(256), 0, stream>>>(part, bvec, out);
}